// Round 6
// baseline (3231.187 us; speedup 1.0000x reference)
//
#include <hip/hip_runtime.h>
#include <stdint.h>

// ---------------- problem constants ----------------
#define TSTEPS 256
#define KB0  36      // (128+1024)/32 k-blocks, layer 0
#define KB1  64      // (1024+1024)/32 k-blocks, layer 1

// workspace layout (bytes)
#define WPK0_OFF 0ull
#define WPK1_OFF 9437184ull
#define A0_OFF   26214400ull
#define A1_OFF   63963136ull
#define BIAS_OFF 131072000ull
#define FLG_OFF  131104768ull

typedef __attribute__((ext_vector_type(8))) short bf16x8;
typedef __attribute__((ext_vector_type(4))) float f32x4;

__device__ __forceinline__ unsigned short f2bf(float x) {
  unsigned int u = __float_as_uint(x);
  u = (u + 0x7FFFu + ((u >> 16) & 1u)) >> 16;
  return (unsigned short)u;
}

// position shuffle inside a 32-k block so each lane's 8 fragment elements
// (k in {4g..4g+3} U {16+4g..16+4g+3}, g = lane>>4) are 16B-contiguous.
__device__ __forceinline__ int kpos(int k) {
  return (((k & 15) >> 2) << 3) + (((k >> 4) & 1) << 2) + (k & 3);
}
__device__ __forceinline__ int kpos4(int k) {  // k 4-aligned
  return (((k & 15) >> 2) << 3) + (((k >> 4) & 1) << 2);
}

__device__ __forceinline__ float sigm(float z) {
  return 1.0f / (1.0f + __expf(-z));
}

// sc1 write-through store helpers (reach the coherent point, no dirty L2 line)
__device__ __forceinline__ void st_u32(unsigned int* p, unsigned int v) {
  __hip_atomic_store(p, v, __ATOMIC_RELAXED, __HIP_MEMORY_SCOPE_AGENT);
}
__device__ __forceinline__ void st_f32(float* p, float v) {
  __hip_atomic_store(p, v, __ATOMIC_RELAXED, __HIP_MEMORY_SCOPE_AGENT);
}

// per-thread relaxed poll (sc0 sc1 load: reads coherent point, no inv)
__device__ __forceinline__ void spin1(unsigned int* p, unsigned int tgt) {
  while (__hip_atomic_load(p, __ATOMIC_RELAXED, __HIP_MEMORY_SCOPE_AGENT) < tgt)
    __builtin_amdgcn_s_sleep(2);
}

// ---------------- pre-kernels (ALL stores sc1 write-through) ----------------
__global__ void k_init(const float* __restrict__ bih0, const float* __restrict__ bhh0,
                       const float* __restrict__ bih1, const float* __restrict__ bhh1,
                       float* __restrict__ bias, unsigned int* __restrict__ flg) {
  int i = blockIdx.x * 256 + threadIdx.x;   // 8192 threads
  st_u32(flg + i, 0u);                      // flags0[128*32] + flags1[128*32]
  if (i < 4096) {
    st_f32(bias + i,        bih0[i] + bhh0[i]);
    st_f32(bias + 4096 + i, bih1[i] + bhh1[i]);
  }
}

// pack [Wih | Whh] (4096 x K) -> fragment-native bf16, 2 k-elems per thread
__global__ void k_packW(const float* __restrict__ Wih, const float* __restrict__ Whh,
                        const int Kih, const int KB, unsigned short* __restrict__ dst) {
  const int K = KB << 5, Kh = K >> 1;
  const int total = K << 11;                 // 4096*K/2 pairs
  int i = blockIdx.x * 256 + threadIdx.x;
  if (i >= total) return;
  int n = i / Kh, kp = i - n * Kh, k = kp << 1;
  float w0 = (k < Kih) ? Wih[n * Kih + k] : Whh[n * 1024 + (k - Kih)];
  float w1 = (k + 1 < Kih) ? Wih[n * Kih + k + 1] : Whh[n * 1024 + (k + 1 - Kih)];
  int gt = n >> 10, hcol = n & 1023;
  int wgi = hcol >> 3, j = hcol & 7;
  int nt = gt >> 1;
  int l15 = ((gt & 1) << 3) | j;             // ntile0: i|f cols, ntile1: g|o cols
  int kb = k >> 5;
  size_t idx = ((size_t)((wgi * 2 + nt) * KB + kb) << 9) + (l15 << 5) + kpos(k & 31);
  st_u32((unsigned int*)(dst + idx),
         ((unsigned int)f2bf(w1) << 16) | f2bf(w0));
}

// pack x (B,T,V) into A0(t) k=0..127 region, 2 v-elems per thread
__global__ void k_packX(const float* __restrict__ x, unsigned short* __restrict__ a0) {
  int i = blockIdx.x * 256 + threadIdx.x;    // 1,048,576 threads
  int v = (i & 63) << 1, t = (i >> 6) & 255, b = i >> 14;
  const float* xp = x + (size_t)b * 32768 + t * 128 + v;
  size_t idx = (size_t)t * 73728 + (size_t)(((v >> 5) << 6) + b) * 32 + kpos(v & 31);
  st_u32((unsigned int*)(a0 + idx),
         ((unsigned int)f2bf(xp[1]) << 16) | f2bf(xp[0]));
}

// initial h: h[0] -> A0(0) k=128+hc ; h[1] -> A1(0) k=1024+hc (2 hc per thread)
__global__ void k_packH(const float* __restrict__ h,
                        unsigned short* __restrict__ a0, unsigned short* __restrict__ a1) {
  int i = blockIdx.x * 256 + threadIdx.x;    // 65536 threads
  int l = i >> 15, b = (i >> 9) & 63, hc = (i & 511) << 1;
  const float* hp = h + (size_t)l * 65536 + (size_t)b * 1024 + hc;
  unsigned int pk = ((unsigned int)f2bf(hp[1]) << 16) | f2bf(hp[0]);
  if (l == 0) {
    int k = 128 + hc;
    st_u32((unsigned int*)(a0 + (size_t)(((k >> 5) << 6) + b) * 32 + kpos(k & 31)), pk);
  } else {
    int k = 1024 + hc;
    st_u32((unsigned int*)(a1 + (size_t)(((k >> 5) << 6) + b) * 32 + kpos(k & 31)), pk);
  }
}

// ---------------- main persistent kernel ----------------
// 128 WGs/layer; WG owns 8 h-cols (32 z-cols, all 4 gates). Wave wv owns
// batch rows wv*16..+15 over FULL K (no cross-wave reduce). Producers write
// h via sc1 (write-through); consumers use NORMAL cached loads, made safe by
// one agent-acquire (buffer_inv sc1, vmcnt-tracked -> completed before the
// barrier releases) per step. Weights live in LDS, so the inv is ~free.
template <int LAYER>
__device__ __forceinline__ void run_layer(
    const int wg, const int tid,
    const float* __restrict__ c_in, float* __restrict__ out,
    const unsigned short* __restrict__ W,
    unsigned short* __restrict__ a0, unsigned short* __restrict__ a1,
    const float* __restrict__ bias,
    unsigned int* flags0, unsigned int* flags1,
    unsigned short* ldsw, float (*h_lds)[8]) {
  constexpr int KB = LAYER ? KB1 : KB0;
  constexpr int AELEM = KB * 2048;

  const int lane = tid & 63, wv = tid >> 6;
  const int l15 = lane & 15, lg = lane >> 4;
  const int lbo = lane * 8;                   // B fragment offset (LDS lane-linear)

  const unsigned short* Ard = LAYER ? a1 : a0;
  unsigned int* myflag = (LAYER ? flags1 : flags0) + wg * 32;

  // ---- entry acquire: invalidate stale L2 lines (prior replay / pre-kernel)
  if (tid == 0)
    (void)__hip_atomic_load(myflag, __ATOMIC_ACQUIRE, __HIP_MEMORY_SCOPE_AGENT);
  __syncthreads();  // vmcnt(0) before barrier => inv completed

  // ---- stage weight slice into LDS once (dest unit = lane id) ----
  {
    const unsigned short* Wg = W + (size_t)(wg * 2) * KB * 512;
    for (int i = tid; i < KB * 128; i += 256) {
      int u = i & 63;
      *(bf16x8*)(ldsw + (size_t)((((i >> 6) << 6) | ((u & 3) << 4) | (u >> 2)) * 8)) =
          *(const bf16x8*)(Wg + (size_t)i * 8);
    }
  }

  // A fragment: row = wv*16 + l15, k-group lg
  const int arowoff = (wv * 16 + l15) * 32 + lg * 8;

  // gate math (active lanes l15<8): rows brow..brow+3, h-col hc
  const int hc = wg * 8 + l15;
  const int brow = wv * 16 + lg * 4;
  float cc[4];
  float bgi = 0.f, bgf = 0.f, bgg = 0.f, bgo = 0.f;
  if (l15 < 8) {
#pragma unroll
    for (int r = 0; r < 4; ++r)
      cc[r] = c_in[LAYER * 65536 + (brow + r) * 1024 + hc];
    bgi = bias[LAYER * 4096 + 0 * 1024 + hc];
    bgf = bias[LAYER * 4096 + 1 * 1024 + hc];
    bgg = bias[LAYER * 4096 + 2 * 1024 + hc];
    bgo = bias[LAYER * 4096 + 3 * 1024 + hc];
  }

  // h-distribution mapping (tid<128): batch row db, col quad dc0
  const int db = tid >> 1;
  const int dc0 = (tid & 1) * 4;
  const int dhc = wg * 8 + dc0;

  __syncthreads();  // ldsw ready

  for (int t = 0; t < TSTEPS; ++t) {
    // ---- cross-WG wait: relaxed spins, then one acquire (buffer_inv) ----
    if (LAYER == 0) {
      if (t && tid < 128) spin1(flags0 + tid * 32, (unsigned int)t);
    } else {
      if (tid < 128) spin1(flags0 + tid * 32, (unsigned int)(t + 1));
      else if (t)    spin1(flags1 + (tid - 128) * 32, (unsigned int)t);
    }
    __syncthreads();
    if (tid == 0)
      (void)__hip_atomic_load(myflag, __ATOMIC_ACQUIRE, __HIP_MEMORY_SCOPE_AGENT);
    __syncthreads();  // inv complete before any A-load below

    // ---- GEMM: normal cached A-loads (L2-shared across the XCD's WGs) ----
    const bf16x8* Af = (const bf16x8*)(Ard + (size_t)t * AELEM + arowoff);
    f32x4 acc[2][2];
    acc[0][0] = (f32x4){0.f, 0.f, 0.f, 0.f};
    acc[0][1] = (f32x4){0.f, 0.f, 0.f, 0.f};
    acc[1][0] = (f32x4){0.f, 0.f, 0.f, 0.f};
    acc[1][1] = (f32x4){0.f, 0.f, 0.f, 0.f};
#pragma unroll
    for (int kb = 0; kb < KB; ++kb) {
      bf16x8 av = Af[(size_t)kb * 256];
      bf16x8 b0 = *(const bf16x8*)(ldsw + (size_t)kb * 512 + lbo);
      bf16x8 b1 = *(const bf16x8*)(ldsw + (size_t)(KB + kb) * 512 + lbo);
      acc[0][kb & 1] =
          __builtin_amdgcn_mfma_f32_16x16x32_bf16(av, b0, acc[0][kb & 1], 0, 0, 0);
      acc[1][kb & 1] =
          __builtin_amdgcn_mfma_f32_16x16x32_bf16(av, b1, acc[1][kb & 1], 0, 0, 0);
    }
    f32x4 z0 = acc[0][0] + acc[0][1];  // cols: l15<8 gate-i, l15>=8 gate-f
    f32x4 z1 = acc[1][0] + acc[1][1];  // cols: l15<8 gate-g, l15>=8 gate-o

    // ---- xor-8 exchange: bring f (resp. o) to the i (resp. g) lanes ----
    f32x4 zf, zo;
#pragma unroll
    for (int r = 0; r < 4; ++r) {
      zf[r] = __shfl_xor(z0[r], 8, 64);
      zo[r] = __shfl_xor(z1[r], 8, 64);
    }

    // ---- gate math (f32), c in registers across all steps ----
    if (l15 < 8) {
#pragma unroll
      for (int r = 0; r < 4; ++r) {
        float iv = sigm(z0[r] + bgi);
        float fv = sigm(zf[r] + bgf);
        float gv = tanhf(z1[r] + bgg);
        float ov = sigm(zo[r] + bgo);
        cc[r] = fv * cc[r] + iv * gv;
        h_lds[brow + r][l15] = ov * tanhf(cc[r]);
      }
    }
    __syncthreads();  // h_lds tile complete

    // ---- h distribution: packed u64 sc1 write-through stores ----
    if (tid < 128) {
      float4 hf = *(const float4*)&h_lds[db][dc0];
      unsigned long long pk =
          (unsigned long long)(((unsigned int)f2bf(hf.y) << 16) | f2bf(hf.x)) |
          ((unsigned long long)(((unsigned int)f2bf(hf.w) << 16) | f2bf(hf.z)) << 32);
      if (LAYER == 0) {
        int k = dhc;  // h0(t) -> A1(t) first half
        __hip_atomic_store(
            (unsigned long long*)(a1 + (size_t)t * 131072 +
                                  (size_t)(((k >> 5) << 6) + db) * 32 + kpos4(k)),
            pk, __ATOMIC_RELAXED, __HIP_MEMORY_SCOPE_AGENT);
        if (t < TSTEPS - 1) {
          int k2 = 128 + dhc;  // h0(t) -> A0(t+1)
          __hip_atomic_store(
              (unsigned long long*)(a0 + (size_t)(t + 1) * 73728 +
                                    (size_t)(((k2 >> 5) << 6) + db) * 32 + kpos4(k2)),
              pk, __ATOMIC_RELAXED, __HIP_MEMORY_SCOPE_AGENT);
        }
      } else {
        *(float4*)(out + ((size_t)db * 256 + t) * 1024 + dhc) = hf;  // outs f32
        if (t < TSTEPS - 1) {
          int k = 1024 + dhc;  // h1(t) -> A1(t+1) second half
          __hip_atomic_store(
              (unsigned long long*)(a1 + (size_t)(t + 1) * 131072 +
                                    (size_t)(((k >> 5) << 6) + db) * 32 + kpos4(k)),
              pk, __ATOMIC_RELAXED, __HIP_MEMORY_SCOPE_AGENT);
        }
      }
      if (t == TSTEPS - 1)  // final h_f (f32)
        *(float4*)(out + 16777216ull + (size_t)LAYER * 65536 +
                   (size_t)db * 1024 + dhc) = hf;
    }
    if (t == TSTEPS - 1 && l15 < 8) {  // final c_f (f32) from register state
#pragma unroll
      for (int r = 0; r < 4; ++r)
        out[16777216ull + 131072ull + (size_t)LAYER * 65536 +
            (size_t)(brow + r) * 1024 + hc] = cc[r];
    }

    // end barrier: each thread's sc1 stores drained (vmcnt0) before release
    __syncthreads();
    if (tid == 0)
      __hip_atomic_store(myflag, (unsigned int)(t + 1), __ATOMIC_RELAXED,
                         __HIP_MEMORY_SCOPE_AGENT);
  }
}

__global__ __launch_bounds__(256, 1) void lstm_main(
    const float* __restrict__ c_in, float* __restrict__ out,
    const unsigned short* __restrict__ wpk0, const unsigned short* __restrict__ wpk1,
    unsigned short* a0, unsigned short* a1,
    const float* __restrict__ bias, unsigned int* flg) {
  __shared__ unsigned short ldsw[KB1 * 1024];  // 131,072 B weight slice
  __shared__ float h_lds[64][8];               // 2 KB h bounce tile
  int bid = blockIdx.x, tid = threadIdx.x;
  unsigned int* flags0 = flg;
  unsigned int* flags1 = flg + 4096;
  if (bid < 128)
    run_layer<0>(bid, tid, c_in, out, wpk0, a0, a1, bias, flags0, flags1, ldsw, h_lds);
  else
    run_layer<1>(bid - 128, tid, c_in, out, wpk1, a0, a1, bias, flags0, flags1, ldsw, h_lds);
}

// ---------------- host ----------------
extern "C" void kernel_launch(void* const* d_in, const int* in_sizes, int n_in,
                              void* d_out, int out_size, void* d_ws, size_t ws_size,
                              hipStream_t stream) {
  const float* x    = (const float*)d_in[0];
  const float* h    = (const float*)d_in[1];
  const float* c    = (const float*)d_in[2];
  const float* Wih0 = (const float*)d_in[3];
  const float* Whh0 = (const float*)d_in[4];
  const float* bih0 = (const float*)d_in[5];
  const float* bhh0 = (const float*)d_in[6];
  const float* Wih1 = (const float*)d_in[7];
  const float* Whh1 = (const float*)d_in[8];
  const float* bih1 = (const float*)d_in[9];
  const float* bhh1 = (const float*)d_in[10];

  char* ws = (char*)d_ws;
  unsigned short* wpk0 = (unsigned short*)(ws + WPK0_OFF);
  unsigned short* wpk1 = (unsigned short*)(ws + WPK1_OFF);
  unsigned short* a0   = (unsigned short*)(ws + A0_OFF);
  unsigned short* a1   = (unsigned short*)(ws + A1_OFF);
  float* bias          = (float*)(ws + BIAS_OFF);
  unsigned int* flg    = (unsigned int*)(ws + FLG_OFF);
  float* out = (float*)d_out;

  k_init<<<32, 256, 0, stream>>>(bih0, bhh0, bih1, bhh1, bias, flg);
  k_packW<<<9216, 256, 0, stream>>>(Wih0, Whh0, 128, KB0, wpk0);
  k_packW<<<16384, 256, 0, stream>>>(Wih1, Whh1, 1024, KB1, wpk1);
  k_packX<<<4096, 256, 0, stream>>>(x, a0);
  k_packH<<<256, 256, 0, stream>>>(h, a0, a1);
  lstm_main<<<256, 256, 0, stream>>>(c, out, wpk0, wpk1, a0, a1, bias, flg);
}